// Round 14
// baseline (198.603 us; speedup 1.0000x reference)
//
#include <hip/hip_runtime.h>
#include <hip/hip_bf16.h>

// out[b,n] = sum_k x[b,k] * weight[indices[n],k]
// M=64, N=4403, K=4096, fp32 in/out.
// R14: R6 GEMM byte-identical (best: 1104 blocks, 4/CU, 32KB bf16 LDS, XOR
// swz, reg-preloaded a-frags) + split-K "last block reduces" fusion:
// partials -> threadfence -> per-nb device atomic counter; 8th arriver
// reduces its nb and writes out. Kills the reduce dispatch + gap (~4-5us);
// tail reduce overlaps with still-running GEMM blocks. Counters zeroed in
// cvt_x each call (deterministic). R13 lesson kept: x converted ONCE.

#define HIDDEN 4096
#define KSPLIT 8
#define KCHUNK (HIDDEN / KSPLIT)   // 512
#define KSTEPS (KCHUNK / 32)       // 16
#define BATCH  64
#define NTILE  32
#define CNT_OFF (12u << 20)        // counters inside ws
#define XBF_OFF (16u << 20)        // x_bf16 inside ws

using short8 = __attribute__((ext_vector_type(8))) short;
using f32x4  = __attribute__((ext_vector_type(4))) float;

__device__ __forceinline__ short f2bf(float f) {
    __bf16 h = (__bf16)f;                 // pairs into v_cvt_pk_bf16_f32
    return __builtin_bit_cast(short, h);
}

__device__ __forceinline__ short8 cvt8(const f32x4& lo, const f32x4& hi) {
    short8 r;
    r[0] = f2bf(lo[0]); r[1] = f2bf(lo[1]); r[2] = f2bf(lo[2]); r[3] = f2bf(lo[3]);
    r[4] = f2bf(hi[0]); r[5] = f2bf(hi[1]); r[6] = f2bf(hi[2]); r[7] = f2bf(hi[3]);
    return r;
}

// ---- k0: convert x to bf16 + zero the split-K counters ---------------------
__global__ __launch_bounds__(256) void cvt_x(
    const float* __restrict__ x, unsigned short* __restrict__ xbf,
    int* __restrict__ cnt)
{
    if (blockIdx.x == 0) cnt[threadIdx.x] = 0;   // 256 >= NTILES
    const int i = (blockIdx.x * 256 + threadIdx.x) * 8;
    f32x4 a = *(const f32x4*)(x + i);
    f32x4 b = *(const f32x4*)(x + i + 4);
    *(short8*)(xbf + i) = cvt8(a, b);
}

// ---- k1: gathered GEMM (R6 body) + last-block reduce -----------------------
__global__ __launch_bounds__(256, 4) void gather_gemm(
    const float*          __restrict__ weight,   // [11008, 4096] f32
    const unsigned short* __restrict__ xbf,      // [64, 4096] bf16
    const int*            __restrict__ indices,  // [R]
    float*                __restrict__ ws,       // [KSPLIT, 64, R] partials
    int*                  __restrict__ cnt,      // [NTILES] arrival counters
    float*                __restrict__ out,      // [64, R]
    int R)
{
    __shared__ unsigned short wlds[NTILE * KCHUNK];   // 32 KB, XOR-swizzled
    __shared__ int lastflag;

    const int t    = threadIdx.x;
    const int lane = t & 63;
    const int wave = t >> 6;       // 0..3 -> M-tile (16 batch rows each)
    const int nl   = lane & 15;
    const int kg   = lane >> 4;
    const int nb   = blockIdx.x;   // N-tile of 32
    const int kb   = blockIdx.y;   // K-chunk of 512
    const int k0   = kb * KCHUNK;

    // ---- stage weight tile rows nb*32..+31, cols k0..+511, bf16 + XOR swz --
    {
        const int r   = t >> 3;
        const int c   = t & 7;
        const int n   = nb * NTILE + r;
        const int row = indices[n < R ? n : R - 1];
        const float* src = weight + (size_t)row * HIDDEN + k0 + c * 8;
        char* ldsrow = (char*)wlds + r * (KCHUNK * 2);
        const unsigned int swz = (unsigned int)((r & 7) << 4);
#pragma unroll
        for (int s = 0; s < 8; ++s) {
            f32x4 v0 = *(const f32x4*)(src + (size_t)s * 64);
            f32x4 v1 = *(const f32x4*)(src + (size_t)s * 64 + 4);
            short8 h = cvt8(v0, v1);
            const unsigned int bc = (unsigned int)(c * 16 + s * 128);
            *(short8*)(ldsrow + (bc ^ swz)) = h;
        }
    }

    // ---- preload a-frags (x bf16, converted once in cvt_x) -----------------
    const unsigned short* xrow =
        xbf + (size_t)(wave * 16 + nl) * HIDDEN + k0 + kg * 8;
    short8 afr[KSTEPS];
#pragma unroll
    for (int ks = 0; ks < KSTEPS; ++ks)
        afr[ks] = *(const short8*)(xrow + ks * 32);

    __syncthreads();

    // ---- K loop: 2 swizzled ds_read_b128 + 2 MFMA per step -----------------
    f32x4 acc0 = {0.f,0.f,0.f,0.f}, acc1 = {0.f,0.f,0.f,0.f};

#pragma unroll
    for (int ks = 0; ks < KSTEPS; ++ks) {
#pragma unroll
        for (int nf = 0; nf < 2; ++nf) {
            const int rr = nf * 16 + nl;
            const unsigned int bc =
                (unsigned int)(ks * 64 + kg * 16) ^ (unsigned int)((rr & 7) << 4);
            short8 b = *(const short8*)((const char*)wlds + rr * (KCHUNK * 2) + bc);
            f32x4& acc = nf == 0 ? acc0 : acc1;
            acc = __builtin_amdgcn_mfma_f32_16x16x32_bf16(afr[ks], b, acc, 0, 0, 0);
        }
    }

    // ---- store partials: C/D col = nl (n), row = kg*4 + r (batch) ----------
    float* part = ws + (size_t)kb * BATCH * R;
    f32x4 accs[2] = {acc0, acc1};
#pragma unroll
    for (int nf = 0; nf < 2; ++nf) {
        const int nn = nb * NTILE + nf * 16 + nl;
        if (nn < R) {
#pragma unroll
            for (int r = 0; r < 4; ++r) {
                const int brow = wave * 16 + kg * 4 + r;
                part[(size_t)brow * R + nn] = accs[nf][r];
            }
        }
    }

    // ---- split-K completion: 8th arriver for this nb reduces ---------------
    __threadfence();               // release: partials visible device-wide
    __syncthreads();               // all threads' stores fenced
    if (t == 0) {
        const int old = atomicAdd(&cnt[nb], 1);   // device-scope (m20)
        lastflag = (old == KSPLIT - 1) ? 1 : 0;
    }
    __syncthreads();

    if (lastflag) {
        __threadfence();           // acquire: see all blocks' partials
        const int b  = t >> 2;                    // 0..63
        const int n0 = nb * NTILE + (t & 3) * 8;  // 8 n per thread
#pragma unroll
        for (int j = 0; j < 8; ++j) {
            const int n = n0 + j;
            if (n < R) {
                float s = 0.f;
#pragma unroll
                for (int k2 = 0; k2 < KSPLIT; ++k2)
                    s += ws[(size_t)k2 * BATCH * R + (size_t)b * R + n];
                out[(size_t)b * R + n] = s;
            }
        }
    }
}

extern "C" void kernel_launch(void* const* d_in, const int* in_sizes, int n_in,
                              void* d_out, int out_size, void* d_ws, size_t ws_size,
                              hipStream_t stream) {
    const float* x       = (const float*)d_in[0];
    const float* weight  = (const float*)d_in[1];
    const int*   indices = (const int*)d_in[2];
    float*       out     = (float*)d_out;
    float*       ws      = (float*)d_ws;
    int*         cnt     = (int*)((char*)d_ws + CNT_OFF);
    unsigned short* xbf  = (unsigned short*)((char*)d_ws + XBF_OFF);

    const int R  = in_sizes[2];                   // 4403
    const int nb = (R + NTILE - 1) / NTILE;       // 138

    cvt_x<<<dim3((BATCH * HIDDEN) / (256 * 8)), dim3(256), 0, stream>>>(x, xbf, cnt);
    gather_gemm<<<dim3(nb, KSPLIT), dim3(256), 0, stream>>>(
        weight, xbf, indices, ws, cnt, out, R);
}